// Round 4
// 206.520 us; speedup vs baseline: 1.1664x; 1.1664x over previous
//
#include <hip/hip_runtime.h>
#include <cstdint>
#include <cstddef>

// ---------------- numeric constants (fp64, 17 sig digits) ----------------
// psp IIR: d = exp(-1/tau), c = e/tau   (alpha kernel k(t) = c * t * d^t)
#define D_TAU1 0.36787944117144233   // exp(-1)
#define C_TAU1 2.7182818284590452    // e
#define D_TAU2 0.60653065971263342   // exp(-1/2)
#define C_TAU2 1.3591409142295226    // e/2
#define D_TAU4 0.77880078307140487   // exp(-1/4)
#define C_TAU4 0.67957045711476131   // e/4
// refractory: dr = exp(-1/tauRef), d32 = dr^32, cr = -2*theta*scaleRef*e/tauRef
#define DR1   0.36787944117144233
#define D32_1 1.2664165549094176e-14 // exp(-32)
#define CR1   -163.09690970754271    // -60e   (theta=30, tauRef=1)
#define DR2   0.60653065971263342
#define D32_2 1.1253517471925911e-7  // exp(-16)
#define CR2   -135.91409142295226    // -50e   (theta=50, tauRef=2)
#define DR3   0.77880078307140487
#define D32_3 3.3546262790251184e-4  // exp(-8)
#define CR3   -135.91409142295226    // -50e   (theta=100, tauRef=4)
// E-state derived constants (compile-time f64 folds)
#define MD1   (-(D32_1 * CR1))
#define M32_1 (-(32.0 * D32_1 * CR1))
#define MD2   (-(D32_2 * CR2))
#define M32_2 (-(32.0 * D32_2 * CR2))
#define MD3   (-(D32_3 * CR3))
#define M32_3 (-(32.0 * D32_3 * CR3))

// ---------------- spike scan, 2-state refractory form (all f64) ----------
// P = cr*(Brf - d32*(Bd+32*Ad)), Q = cr*(Arf - d32*Ad)  (exact algebra vs
// the verified 4-state form; rounding differs ~1e-16 rel — safe, f64 only).
// R = P;  P <- dr*(P+Q) - 32*d32*cr*sd;  Q <- dr*Q + cr*s - d32*cr*sd.
struct SpikeE { double P, Q; unsigned h0, h1; };

__device__ __forceinline__ void spike_half0(SpikeE& st, double u, int tt,
    double th, double dr, double CR) {
  const double v = u + st.P;
  const bool fire = (v >= th);
  const double u2 = st.P + st.Q;
  st.P = dr * u2;
  st.Q = dr * st.Q + (fire ? CR : 0.0);
  if (fire) st.h0 |= (1u << tt);
}
__device__ __forceinline__ void spike_half1(SpikeE& st, double u, int tt,
    double th, double dr, double CR, double MD, double M32) {
  const double v = u + st.P;
  const bool fire = (v >= th);
  const bool sd = (st.h0 >> tt) & 1u;        // spike at t-32
  const double u2 = st.P + st.Q;
  st.P = dr * u2 + (sd ? M32 : 0.0);
  st.Q = dr * st.Q + (fire ? (sd ? (CR + MD) : CR) : (sd ? MD : 0.0));
  if (fire) st.h1 |= (1u << tt);
}

// ---------------- geometry / workspace (4.5 MB, lifetime-aliased) --------
// IM  [0.0,0.5) MB : (16 img, 4096 sites) u64 input masks   — live all
// S1  [0.5,2.5) MB : (64 img, 4096 sites) u64 layer-1 masks — K2 -> K2b
// S1C [2.5,4.5) MB : (8 b, 4096 sites, 8) channel bytes     — K2b -> K3
// IMT = alias of S1C[0,0.5MB): x-transposed input           — K1 -> K2
//       (dead before K2b writes S1C; stream serializes kernels)
// S2T = alias of S1: (16 img,128 y,64 t,2 xh) transposed l2 — K3 -> K4
//       (S1 dead after K2b)

// K1: input spikes -> site masks + x-transposed bitplanes (via ballot).
__global__ __launch_bounds__(256) void k_masks(const float* __restrict__ x,
                                               unsigned long long* __restrict__ im,
                                               unsigned long long* __restrict__ imt) {
  const int idx = blockIdx.x * 256 + threadIdx.x;  // (bc,y,x), x fastest
  const float* xin = x + (size_t)idx * 64;
  unsigned long long hist = 0ull;
  for (int t4 = 0; t4 < 16; ++t4) {
    const float4 v = reinterpret_cast<const float4*>(xin)[t4];
    if (v.x != 0.0f) hist |= 1ull << (t4 * 4 + 0);
    if (v.y != 0.0f) hist |= 1ull << (t4 * 4 + 1);
    if (v.z != 0.0f) hist |= 1ull << (t4 * 4 + 2);
    if (v.w != 0.0f) hist |= 1ull << (t4 * 4 + 3);
  }
  im[idx] = hist;
  // wave = one y-row (64 lanes = 64 x). Transpose via ballot: word over x.
  const int lane = threadIdx.x & 63;
  const int bc = idx >> 12, y = (idx >> 6) & 63;
  unsigned long long myw = 0ull;
  for (int t = 0; t < 64; ++t) {
    const unsigned long long bal = __ballot((int)((hist >> t) & 1ull));
    if (lane == t) myw = bal;
  }
  imt[((size_t)bc * 64 + y) * 64 + lane] = myw;
}

// ---- K2: spike1 = spike(psp1(conv5x5(input))) — row-sum tables in LDS ----
__global__ __launch_bounds__(256, 4) void k_conv1_spike(
    const unsigned long long* __restrict__ imt, const float* __restrict__ w1f,
    unsigned long long* __restrict__ s1) {
  __shared__ double tbl[10][32];                   // [ch*5+r][5-bit field]
  __shared__ unsigned long long rows[16][64][2];   // [ch*8+rr][t][shift-variant]
  const int tid = threadIdx.x;
  const int o = blockIdx.y, b = blockIdx.z;
  const int y0 = blockIdx.x * 4;                   // 4 output rows per block
  // weight tables: entry = sum of pre-scaled f64 weights over set bits,
  // ascending tap order (f64 reassociation vs baseline chain — safe).
  for (int i = tid; i < 320; i += 256) {
    const int f = i & 31, rr = i >> 5;             // rr = ch*5 + r
    double s = 0.0;
#pragma unroll
    for (int k = 0; k < 5; ++k)
      if ((f >> k) & 1) s += (double)w1f[o * 50 + rr * 5 + k] * C_TAU1;
    tbl[rr][f] = s;
  }
  // stage x-transposed rows, pre-shifted two ways:
  //  var0 = w<<2 : site x-2 at bit x      (x in 0..31)
  //  var1 = w>>30: site x-2 at bit x-32   (x in 32..63)
  for (int i = tid; i < 1024; i += 256) {
    const int t = i & 63, row = i >> 6;            // row = ch*8 + rr
    const int ch = row >> 3, rr = row & 7;
    const int yr = y0 - 2 + rr;
    unsigned long long w = 0ull;
    if ((unsigned)yr < 64u)
      w = imt[((size_t)(b * 2 + ch) * 64 + yr) * 64 + t];
    rows[row][t][0] = w << 2;
    rows[row][t][1] = w >> 30;
  }
  __syncthreads();
  const int x = tid & 63, dy = tid >> 6;           // dy = 0..3
  const int y = y0 + dy;
  const int sh = x & 31, wsel = x >> 5;
  double A = 0.0, B = 0.0;
  SpikeE st = {0.0, 0.0, 0u, 0u};
  for (int tt = 0; tt < 32; ++tt) {
    double d = 0.0;
#pragma unroll
    for (int ch = 0; ch < 2; ++ch)
#pragma unroll
      for (int r = 0; r < 5; ++r) {
        const unsigned long long w = rows[ch * 8 + dy + r][tt][wsel];
        const unsigned f = ((unsigned)(w >> sh)) & 31u;
        d += tbl[ch * 5 + r][f];
      }
    B = D_TAU1 * (B + A); A = D_TAU1 * A + d;
    spike_half0(st, B, tt, 30.0, DR1, CR1);
  }
  for (int tt = 0; tt < 32; ++tt) {
    double d = 0.0;
#pragma unroll
    for (int ch = 0; ch < 2; ++ch)
#pragma unroll
      for (int r = 0; r < 5; ++r) {
        const unsigned long long w = rows[ch * 8 + dy + r][tt + 32][wsel];
        const unsigned f = ((unsigned)(w >> sh)) & 31u;
        d += tbl[ch * 5 + r][f];
      }
    B = D_TAU1 * (B + A); A = D_TAU1 * A + d;
    spike_half1(st, B, tt, 30.0, DR1, CR1, MD1, M32_1);
  }
  s1[((size_t)(b * 8 + o)) * 4096 + y * 64 + x] =
      ((unsigned long long)st.h1 << 32) | (unsigned long long)st.h0;
}

// ---- K2b: pack 8 s1 channels into channel-bytes per (site,t) ----
__global__ __launch_bounds__(256) void k_s1_bytes(
    const unsigned long long* __restrict__ s1,
    unsigned long long* __restrict__ s1c) {
  const int idx = blockIdx.x * 256 + threadIdx.x;  // b*4096 + site
  const int b = idx >> 12, site = idx & 4095;
  unsigned long long m[8];
#pragma unroll
  for (int o = 0; o < 8; ++o) m[o] = s1[((size_t)b * 8 + o) * 4096 + site];
#pragma unroll
  for (int j = 0; j < 8; ++j) {
    unsigned long long xx = 0ull;
#pragma unroll
    for (int o = 0; o < 8; ++o)
      xx |= ((m[o] >> (8 * j)) & 0xFFull) << (8 * o);
    // 8x8 bit transpose (rows=channels -> rows=t): bit(8k+o) = bit(8o+k)
    unsigned long long t;
    t = (xx ^ (xx >> 7)) & 0x00AA00AA00AA00AAull; xx = xx ^ t ^ (t << 7);
    t = (xx ^ (xx >> 14)) & 0x0000CCCC0000CCCCull; xx = xx ^ t ^ (t << 14);
    t = (xx ^ (xx >> 28)) & 0x00000000F0F0F0F0ull; xx = xx ^ t ^ (t << 28);
    s1c[(size_t)idx * 8 + j] = xx;
  }
}

// ---- K3: spike2 = spike(deconv2x2(psp2(s1))) — one 256-entry lookup/t ----
__global__ __launch_bounds__(256, 4) void k_deconv_spike(
    const unsigned long long* __restrict__ s1c, const float* __restrict__ w2f,
    unsigned long long* __restrict__ s2t) {
  __shared__ double tbl[4][256];                   // [(ii*2+jj)][channel byte]
  const int tid = threadIdx.y * 128 + threadIdx.x;
  const int b = blockIdx.z >> 1, o = blockIdx.z & 1;
  for (int i = tid; i < 1024; i += 256) {
    const int f = i & 255, q = i >> 8, ii = q >> 1, jj = q & 1;
    double s = 0.0;
#pragma unroll
    for (int c = 0; c < 8; ++c)
      if ((f >> c) & 1) s += (double)w2f[((c * 2 + o) * 2 + ii) * 2 + jj] * C_TAU2;
    tbl[q][f] = s;
  }
  __syncthreads();
  const int X = threadIdx.x, Y = blockIdx.x * 2 + threadIdx.y;
  const int xi = X >> 1, yi = Y >> 1;
  const double* tq = tbl[(Y & 1) * 2 + (X & 1)];
  const unsigned long long* cw = s1c + ((size_t)b * 4096 + yi * 64 + xi) * 8;
  const unsigned long long c0 = cw[0], c1 = cw[1], c2 = cw[2], c3 = cw[3],
                           c4 = cw[4], c5 = cw[5], c6 = cw[6], c7 = cw[7];
  double A = 0.0, B = 0.0;
  SpikeE st = {0.0, 0.0, 0u, 0u};
#pragma unroll
  for (int tt = 0; tt < 32; ++tt) {
    const unsigned long long cword =
        (tt < 8) ? c0 : (tt < 16) ? c1 : (tt < 24) ? c2 : c3;
    const unsigned f = ((unsigned)(cword >> ((tt & 7) * 8))) & 255u;
    const double d = tq[f];
    B = D_TAU2 * (B + A); A = D_TAU2 * A + d;
    spike_half0(st, B, tt, 50.0, DR2, CR2);
  }
#pragma unroll
  for (int tt = 0; tt < 32; ++tt) {
    const unsigned long long cword =
        (tt < 8) ? c4 : (tt < 16) ? c5 : (tt < 24) ? c6 : c7;
    const unsigned f = ((unsigned)(cword >> ((tt & 7) * 8))) & 255u;
    const double d = tq[f];
    B = D_TAU2 * (B + A); A = D_TAU2 * A + d;
    spike_half1(st, B, tt, 50.0, DR2, CR2, MD2, M32_2);
  }
  // ballot-transpose: wave = (Y, x-half); word over 64 x-lanes per t.
  const int lane = threadIdx.x & 63, xh = threadIdx.x >> 6;
  unsigned long long myw = 0ull;
  for (int t = 0; t < 32; ++t) {
    const unsigned long long bal = __ballot((int)((st.h0 >> t) & 1u));
    if (lane == t) myw = bal;
  }
  for (int t = 0; t < 32; ++t) {
    const unsigned long long bal = __ballot((int)((st.h1 >> t) & 1u));
    if (lane == t + 32) myw = bal;
  }
  s2t[(((size_t)(b * 2 + o) * 128 + Y) * 64 + lane) * 2 + xh] = myw;
}

// ---- K4: out = spike(conv3x3(psp3(s2)) + psp1(bilinear(input))) ----
__global__ __launch_bounds__(256, 4) void k_conv3_spike_out(
    const unsigned long long* __restrict__ s2t, const float* __restrict__ w3f,
    const unsigned long long* __restrict__ im, float* __restrict__ out) {
  __shared__ double tbl[3][64];                    // [ky][f0 | f1<<3]
  __shared__ unsigned long long rows[8][64][4];    // [ch*4+rr][t][variant]
  const int tid = threadIdx.y * 128 + threadIdx.x;
  const int b = blockIdx.z >> 1, o = blockIdx.z & 1;
  const int Y0 = blockIdx.x * 2;
  for (int i = tid; i < 192; i += 256) {
    const int f = i & 63, ky = i >> 6;
    double s = 0.0;
#pragma unroll
    for (int cc = 0; cc < 2; ++cc)
#pragma unroll
      for (int kx = 0; kx < 3; ++kx)
        if ((f >> (cc * 3 + kx)) & 1)
          s += (double)w3f[o * 18 + cc * 9 + ky * 3 + kx] * C_TAU4;
    tbl[ky][f] = s;
  }
  // stage x-transposed 128-wide rows as 4 pre-shifted u64 windows:
  //  var v serves x in [32v, 32v+31]; site x-1+k at bit (x&31)+k.
  for (int i = tid; i < 512; i += 256) {
    const int t = i & 63, row = i >> 6;            // row = ch*4 + rr
    const int ch = row >> 2, rr = row & 3;
    const int yn = Y0 - 1 + rr;
    unsigned long long w0 = 0ull, w1 = 0ull;
    if ((unsigned)yn < 128u) {
      const size_t base = (((size_t)(b * 2 + ch) * 128 + yn) * 64 + t) * 2;
      w0 = s2t[base]; w1 = s2t[base + 1];
    }
    rows[row][t][0] = w0 << 1;
    rows[row][t][1] = (w0 >> 31) | (w1 << 33);
    rows[row][t][2] = (w0 >> 63) | (w1 << 1);
    rows[row][t][3] = w1 >> 31;
  }
  __syncthreads();
  const int X = threadIdx.x;
  const int dyy = threadIdx.y;
  const int Y = Y0 + dyy;
  const int sh = X & 31, wsel = X >> 5;
  // bilinear 2x skip taps (half-pixel, clamped) — baseline-exact f64
  const int y0 = (Y - 1) >> 1, x0 = (X - 1) >> 1;
  const double wy1 = (Y & 1) ? 0.25 : 0.75, wy0 = 1.0 - wy1;
  const double wx1 = (X & 1) ? 0.25 : 0.75, wx0 = 1.0 - wx1;
  const int iy0 = max(y0, 0), iy1 = min(y0 + 1, 63);
  const int ix0 = max(x0, 0), ix1 = min(x0 + 1, 63);
  const double ws[4] = { wy0 * wx0 * C_TAU1, wy0 * wx1 * C_TAU1,
                         wy1 * wx0 * C_TAU1, wy1 * wx1 * C_TAU1 };
  const unsigned long long* imb = im + (size_t)(b * 2 + o) * 4096;
  const unsigned long long ms[4] = {
    imb[(size_t)iy0 * 64 + ix0], imb[(size_t)iy0 * 64 + ix1],
    imb[(size_t)iy1 * 64 + ix0], imb[(size_t)iy1 * 64 + ix1] };
  unsigned mlo[4], mhi[4];
#pragma unroll
  for (int i = 0; i < 4; ++i) {
    mlo[i] = (unsigned)(ms[i] & 0xFFFFFFFFull);
    mhi[i] = (unsigned)(ms[i] >> 32);
  }
  double Ac = 0.0, Bc = 0.0, As = 0.0, Bs = 0.0;
  SpikeE st = {0.0, 0.0, 0u, 0u};
  for (int tt = 0; tt < 32; ++tt) {
    double dc = 0.0;
#pragma unroll
    for (int ky = 0; ky < 3; ++ky) {
      const unsigned long long wa = rows[0 * 4 + dyy + ky][tt][wsel];
      const unsigned long long wb = rows[1 * 4 + dyy + ky][tt][wsel];
      const unsigned f = (((unsigned)(wa >> sh)) & 7u)
                       | ((((unsigned)(wb >> sh)) & 7u) << 3);
      dc += tbl[ky][f];
    }
    double e = 0.0;
#pragma unroll
    for (int i = 0; i < 4; ++i)
      e += ws[i] * (double)((mlo[i] >> tt) & 1u);
    Bc = D_TAU4 * (Bc + Ac); Ac = D_TAU4 * Ac + dc;
    Bs = D_TAU1 * (Bs + As); As = D_TAU1 * As + e;
    spike_half0(st, Bc + Bs, tt, 100.0, DR3, CR3);
  }
  for (int tt = 0; tt < 32; ++tt) {
    double dc = 0.0;
#pragma unroll
    for (int ky = 0; ky < 3; ++ky) {
      const unsigned long long wa = rows[0 * 4 + dyy + ky][tt + 32][wsel];
      const unsigned long long wb = rows[1 * 4 + dyy + ky][tt + 32][wsel];
      const unsigned f = (((unsigned)(wa >> sh)) & 7u)
                       | ((((unsigned)(wb >> sh)) & 7u) << 3);
      dc += tbl[ky][f];
    }
    double e = 0.0;
#pragma unroll
    for (int i = 0; i < 4; ++i)
      e += ws[i] * (double)((mhi[i] >> tt) & 1u);
    Bc = D_TAU4 * (Bc + Ac); Ac = D_TAU4 * Ac + dc;
    Bs = D_TAU1 * (Bs + As); As = D_TAU1 * As + e;
    spike_half1(st, Bc + Bs, tt, 100.0, DR3, CR3, MD3, M32_3);
  }
  const unsigned long long h =
      ((unsigned long long)st.h1 << 32) | (unsigned long long)st.h0;
  float* op = out + (((size_t)(b * 2 + o) * 128 + Y) * 128 + X) * 64;
#pragma unroll
  for (int t4 = 0; t4 < 16; ++t4) {
    float4 v;
    v.x = ((h >> (t4 * 4 + 0)) & 1ull) ? 1.0f : 0.0f;
    v.y = ((h >> (t4 * 4 + 1)) & 1ull) ? 1.0f : 0.0f;
    v.z = ((h >> (t4 * 4 + 2)) & 1ull) ? 1.0f : 0.0f;
    v.w = ((h >> (t4 * 4 + 3)) & 1ull) ? 1.0f : 0.0f;
    reinterpret_cast<float4*>(op)[t4] = v;
  }
}

extern "C" void kernel_launch(void* const* d_in, const int* in_sizes, int n_in,
                              void* d_out, int out_size, void* d_ws, size_t ws_size,
                              hipStream_t stream) {
  const float* spikeIn = (const float*)d_in[0];   // (8,2,64,64,64) fp32
  const float* w1 = (const float*)d_in[1];        // (8,2,5,5)
  const float* w2 = (const float*)d_in[2];        // (8,2,2,2) = (in,out,i,j)
  const float* w3 = (const float*)d_in[3];        // (2,2,3,3)
  float* out = (float*)d_out;                     // (8,2,128,128,64) fp32

  // 4.5 MB total with lifetime-based aliasing (peak live set = 4.5 MB):
  unsigned long long* IM  = (unsigned long long*)d_ws;       // [0.0,0.5) MB
  unsigned long long* S1  = IM + (size_t)16 * 4096;          // [0.5,2.5) MB
  unsigned long long* S1C = S1 + (size_t)64 * 4096;          // [2.5,4.5) MB
  unsigned long long* IMT = S1C;   // alias: dead before K2b writes S1C
  unsigned long long* S2T = S1;    // alias: S1 dead after K2b

  k_masks<<<dim3(256), dim3(256), 0, stream>>>(spikeIn, IM, IMT);
  k_conv1_spike<<<dim3(16, 8, 8), dim3(256), 0, stream>>>(IMT, w1, S1);
  k_s1_bytes<<<dim3(128), dim3(256), 0, stream>>>(S1, S1C);
  k_deconv_spike<<<dim3(64, 1, 16), dim3(128, 2), 0, stream>>>(S1C, w2, S2T);
  k_conv3_spike_out<<<dim3(64, 1, 16), dim3(128, 2), 0, stream>>>(S2T, w3, IM, out);
}

// Round 5
// 173.991 us; speedup vs baseline: 1.3845x; 1.1870x over previous
//
#include <hip/hip_runtime.h>
#include <cstdint>
#include <cstddef>

// ---------------- numeric constants (fp64, 17 sig digits) ----------------
// psp IIR: d = exp(-1/tau), c = e/tau   (alpha kernel k(t) = c * t * d^t)
#define D_TAU1 0.36787944117144233   // exp(-1)
#define C_TAU1 2.7182818284590452    // e
#define D_TAU2 0.60653065971263342   // exp(-1/2)
#define C_TAU2 1.3591409142295226    // e/2
#define D_TAU4 0.77880078307140487   // exp(-1/4)
#define C_TAU4 0.67957045711476131   // e/4
// refractory: dr = exp(-1/tauRef), d32 = dr^32, cr = -2*theta*scaleRef*e/tauRef
#define DR1   0.36787944117144233
#define D32_1 1.2664165549094176e-14 // exp(-32)
#define CR1   -163.09690970754271    // -60e   (theta=30, tauRef=1)
#define DR2   0.60653065971263342
#define D32_2 1.1253517471925911e-7  // exp(-16)
#define CR2   -135.91409142295226    // -50e   (theta=50, tauRef=2)
#define DR3   0.77880078307140487
#define D32_3 3.3546262790251184e-4  // exp(-8)
#define CR3   -135.91409142295226    // -50e   (theta=100, tauRef=4)
// E-state derived constants (compile-time f64 folds)
#define MD1   (-(D32_1 * CR1))
#define M32_1 (-(32.0 * D32_1 * CR1))
#define MD2   (-(D32_2 * CR2))
#define M32_2 (-(32.0 * D32_2 * CR2))
#define MD3   (-(D32_3 * CR3))
#define M32_3 (-(32.0 * D32_3 * CR3))

// ---------------- spike scan, 2-state refractory form (all f64) ----------
// P = cr*(Brf - d32*(Bd+32*Ad)), Q = cr*(Arf - d32*Ad)  (exact algebra vs
// the verified 4-state form; rounding differs ~1e-16 rel — safe, f64 only).
struct SpikeE { double P, Q; unsigned h0, h1; };

__device__ __forceinline__ void spike_half0(SpikeE& st, double u, int tt,
    double th, double dr, double CR) {
  const double v = u + st.P;
  const bool fire = (v >= th);
  const double u2 = st.P + st.Q;
  st.P = dr * u2;
  st.Q = dr * st.Q + (fire ? CR : 0.0);
  if (fire) st.h0 |= (1u << tt);
}
__device__ __forceinline__ void spike_half1(SpikeE& st, double u, int tt,
    double th, double dr, double CR, double MD, double M32) {
  const double v = u + st.P;
  const bool fire = (v >= th);
  const bool sd = (st.h0 >> tt) & 1u;        // spike at t-32
  const double u2 = st.P + st.Q;
  st.P = dr * u2 + (sd ? M32 : 0.0);
  st.Q = dr * st.Q + (fire ? (sd ? (CR + MD) : CR) : (sd ? MD : 0.0));
  if (fire) st.h1 |= (1u << tt);
}

// ---------------- geometry / workspace (4.5 MB, lifetime-aliased) --------
// IM  [0.0,0.5) MB : (16 img, 4096 sites) u64 input masks   — live all
// S1  [0.5,2.5) MB : (64 img, 4096 sites) u64 layer-1 masks — K2 -> K2b
// S1C [2.5,4.5) MB : (8 b, 4096 sites, 8) channel bytes     — K2b -> K3
// IMT = alias of S1C[0,0.5MB): x-transposed input           — K1 -> K2
// S2T = alias of S1: (16 img, 128 y, 2 xh, 64 t)            — K3 -> K4
//       layout [y][xh][t]: dense writes in K3, dense reads in K4

// K1: input spikes -> site masks + x-transposed bitplanes (via ballot).
__global__ __launch_bounds__(256) void k_masks(const float* __restrict__ x,
                                               unsigned long long* __restrict__ im,
                                               unsigned long long* __restrict__ imt) {
  const int idx = blockIdx.x * 256 + threadIdx.x;  // (bc,y,x), x fastest
  const float* xin = x + (size_t)idx * 64;
  unsigned long long hist = 0ull;
  for (int t4 = 0; t4 < 16; ++t4) {
    const float4 v = reinterpret_cast<const float4*>(xin)[t4];
    if (v.x != 0.0f) hist |= 1ull << (t4 * 4 + 0);
    if (v.y != 0.0f) hist |= 1ull << (t4 * 4 + 1);
    if (v.z != 0.0f) hist |= 1ull << (t4 * 4 + 2);
    if (v.w != 0.0f) hist |= 1ull << (t4 * 4 + 3);
  }
  im[idx] = hist;
  // wave = one y-row (64 lanes = 64 x). Transpose via ballot: word over x.
  const int lane = threadIdx.x & 63;
  const int bc = idx >> 12, y = (idx >> 6) & 63;
  unsigned long long myw = 0ull;
  for (int t = 0; t < 64; ++t) {
    const unsigned long long bal = __ballot((int)((hist >> t) & 1ull));
    if (lane == t) myw = bal;
  }
  imt[((size_t)bc * 64 + y) * 64 + lane] = myw;
}

// ---- K2: spike1 = spike(psp1(conv5x5(input))) — row-sum tables in LDS ----
__global__ __launch_bounds__(256, 4) void k_conv1_spike(
    const unsigned long long* __restrict__ imt, const float* __restrict__ w1f,
    unsigned long long* __restrict__ s1) {
  __shared__ double tbl[10][32];                   // [ch*5+r][5-bit field]
  __shared__ unsigned long long rows[16][64][2];   // [ch*8+rr][t][shift-variant]
  const int tid = threadIdx.x;
  const int o = blockIdx.y, b = blockIdx.z;
  const int y0 = blockIdx.x * 4;                   // 4 output rows per block
  for (int i = tid; i < 320; i += 256) {
    const int f = i & 31, rr = i >> 5;             // rr = ch*5 + r
    double s = 0.0;
#pragma unroll
    for (int k = 0; k < 5; ++k)
      if ((f >> k) & 1) s += (double)w1f[o * 50 + rr * 5 + k] * C_TAU1;
    tbl[rr][f] = s;
  }
  // stage x-transposed rows, pre-shifted two ways:
  //  var0 = w<<2 : site x-2 at bit x      (x in 0..31)
  //  var1 = w>>30: site x-2 at bit x-32   (x in 32..63)
  for (int i = tid; i < 1024; i += 256) {
    const int t = i & 63, row = i >> 6;            // row = ch*8 + rr
    const int ch = row >> 3, rr = row & 7;
    const int yr = y0 - 2 + rr;
    unsigned long long w = 0ull;
    if ((unsigned)yr < 64u)
      w = imt[((size_t)(b * 2 + ch) * 64 + yr) * 64 + t];
    rows[row][t][0] = w << 2;
    rows[row][t][1] = w >> 30;
  }
  __syncthreads();
  const int x = tid & 63, dy = tid >> 6;           // dy = 0..3
  const int y = y0 + dy;
  const int sh = x & 31, wsel = x >> 5;
  double A = 0.0, B = 0.0;
  SpikeE st = {0.0, 0.0, 0u, 0u};
  for (int tt = 0; tt < 32; ++tt) {
    double d = 0.0;
#pragma unroll
    for (int ch = 0; ch < 2; ++ch)
#pragma unroll
      for (int r = 0; r < 5; ++r) {
        const unsigned long long w = rows[ch * 8 + dy + r][tt][wsel];
        const unsigned f = ((unsigned)(w >> sh)) & 31u;
        d += tbl[ch * 5 + r][f];
      }
    B = D_TAU1 * (B + A); A = D_TAU1 * A + d;
    spike_half0(st, B, tt, 30.0, DR1, CR1);
  }
  for (int tt = 0; tt < 32; ++tt) {
    double d = 0.0;
#pragma unroll
    for (int ch = 0; ch < 2; ++ch)
#pragma unroll
      for (int r = 0; r < 5; ++r) {
        const unsigned long long w = rows[ch * 8 + dy + r][tt + 32][wsel];
        const unsigned f = ((unsigned)(w >> sh)) & 31u;
        d += tbl[ch * 5 + r][f];
      }
    B = D_TAU1 * (B + A); A = D_TAU1 * A + d;
    spike_half1(st, B, tt, 30.0, DR1, CR1, MD1, M32_1);
  }
  s1[((size_t)(b * 8 + o)) * 4096 + y * 64 + x] =
      ((unsigned long long)st.h1 << 32) | (unsigned long long)st.h0;
}

// ---- K2b: pack 8 s1 channels into channel-bytes per (site,t) ----
__global__ __launch_bounds__(256) void k_s1_bytes(
    const unsigned long long* __restrict__ s1,
    unsigned long long* __restrict__ s1c) {
  const int idx = blockIdx.x * 256 + threadIdx.x;  // b*4096 + site
  const int b = idx >> 12, site = idx & 4095;
  unsigned long long m[8];
#pragma unroll
  for (int o = 0; o < 8; ++o) m[o] = s1[((size_t)b * 8 + o) * 4096 + site];
#pragma unroll
  for (int j = 0; j < 8; ++j) {
    unsigned long long xx = 0ull;
#pragma unroll
    for (int o = 0; o < 8; ++o)
      xx |= ((m[o] >> (8 * j)) & 0xFFull) << (8 * o);
    // 8x8 bit transpose (rows=channels -> rows=t): bit(8k+o) = bit(8o+k)
    unsigned long long t;
    t = (xx ^ (xx >> 7)) & 0x00AA00AA00AA00AAull; xx = xx ^ t ^ (t << 7);
    t = (xx ^ (xx >> 14)) & 0x0000CCCC0000CCCCull; xx = xx ^ t ^ (t << 14);
    t = (xx ^ (xx >> 28)) & 0x00000000F0F0F0F0ull; xx = xx ^ t ^ (t << 28);
    s1c[(size_t)idx * 8 + j] = xx;
  }
}

// ---- K3: spike2 = spike(deconv2x2(psp2(s1))) — one 256-entry lookup/t ----
__global__ __launch_bounds__(256, 4) void k_deconv_spike(
    const unsigned long long* __restrict__ s1c, const float* __restrict__ w2f,
    unsigned long long* __restrict__ s2t) {
  __shared__ double tbl[4][256];                   // [(ii*2+jj)][channel byte]
  const int tid = threadIdx.y * 128 + threadIdx.x;
  const int b = blockIdx.z >> 1, o = blockIdx.z & 1;
  for (int i = tid; i < 1024; i += 256) {
    const int f = i & 255, q = i >> 8, ii = q >> 1, jj = q & 1;
    double s = 0.0;
#pragma unroll
    for (int c = 0; c < 8; ++c)
      if ((f >> c) & 1) s += (double)w2f[((c * 2 + o) * 2 + ii) * 2 + jj] * C_TAU2;
    tbl[q][f] = s;
  }
  __syncthreads();
  const int X = threadIdx.x, Y = blockIdx.x * 2 + threadIdx.y;
  const int xi = X >> 1, yi = Y >> 1;
  const double* tq = tbl[(Y & 1) * 2 + (X & 1)];
  const unsigned long long* cw = s1c + ((size_t)b * 4096 + yi * 64 + xi) * 8;
  const unsigned long long c0 = cw[0], c1 = cw[1], c2 = cw[2], c3 = cw[3],
                           c4 = cw[4], c5 = cw[5], c6 = cw[6], c7 = cw[7];
  double A = 0.0, B = 0.0;
  SpikeE st = {0.0, 0.0, 0u, 0u};
#pragma unroll
  for (int tt = 0; tt < 32; ++tt) {
    const unsigned long long cword =
        (tt < 8) ? c0 : (tt < 16) ? c1 : (tt < 24) ? c2 : c3;
    const unsigned f = ((unsigned)(cword >> ((tt & 7) * 8))) & 255u;
    const double d = tq[f];
    B = D_TAU2 * (B + A); A = D_TAU2 * A + d;
    spike_half0(st, B, tt, 50.0, DR2, CR2);
  }
#pragma unroll
  for (int tt = 0; tt < 32; ++tt) {
    const unsigned long long cword =
        (tt < 8) ? c4 : (tt < 16) ? c5 : (tt < 24) ? c6 : c7;
    const unsigned f = ((unsigned)(cword >> ((tt & 7) * 8))) & 255u;
    const double d = tq[f];
    B = D_TAU2 * (B + A); A = D_TAU2 * A + d;
    spike_half1(st, B, tt, 50.0, DR2, CR2, MD2, M32_2);
  }
  // ballot-transpose: wave = (Y, x-half); word over 64 x-lanes per t.
  // Layout [y][xh][t]: lane t writes s2t[..][xh][t] -> dense 512 B per wave.
  const int lane = threadIdx.x & 63, xh = threadIdx.x >> 6;
  unsigned long long myw = 0ull;
  for (int t = 0; t < 32; ++t) {
    const unsigned long long bal = __ballot((int)((st.h0 >> t) & 1u));
    if (lane == t) myw = bal;
  }
  for (int t = 0; t < 32; ++t) {
    const unsigned long long bal = __ballot((int)((st.h1 >> t) & 1u));
    if (lane == t + 32) myw = bal;
  }
  s2t[(((size_t)(b * 2 + o) * 128 + Y) * 2 + xh) * 64 + lane] = myw;
}

// ---- K4: out = spike(conv3x3(psp3(s2)) + psp1(bilinear(input))) ----
__global__ __launch_bounds__(256, 4) void k_conv3_spike_out(
    const unsigned long long* __restrict__ s2t, const float* __restrict__ w3f,
    const unsigned long long* __restrict__ im, float* __restrict__ out) {
  __shared__ double tbl[3][64];                    // [ky][f0 | f1<<3]
  __shared__ unsigned long long rows[8][64][4];    // [ch*4+rr][t][variant]
  const int tid = threadIdx.y * 128 + threadIdx.x;
  const int b = blockIdx.z >> 1, o = blockIdx.z & 1;
  const int Y0 = blockIdx.x * 2;
  for (int i = tid; i < 192; i += 256) {
    const int f = i & 63, ky = i >> 6;
    double s = 0.0;
#pragma unroll
    for (int cc = 0; cc < 2; ++cc)
#pragma unroll
      for (int kx = 0; kx < 3; ++kx)
        if ((f >> (cc * 3 + kx)) & 1)
          s += (double)w3f[o * 18 + cc * 9 + ky * 3 + kx] * C_TAU4;
    tbl[ky][f] = s;
  }
  // stage x-transposed 128-wide rows as 4 pre-shifted u64 windows:
  //  var v serves x in [32v, 32v+31]; site x-1+k at bit (x&31)+k.
  for (int i = tid; i < 512; i += 256) {
    const int t = i & 63, row = i >> 6;            // row = ch*4 + rr
    const int ch = row >> 2, rr = row & 3;
    const int yn = Y0 - 1 + rr;
    unsigned long long w0 = 0ull, w1 = 0ull;
    if ((unsigned)yn < 128u) {
      const size_t base = (((size_t)(b * 2 + ch) * 128 + yn) * 2) * 64 + t;
      w0 = s2t[base]; w1 = s2t[base + 64];
    }
    rows[row][t][0] = w0 << 1;
    rows[row][t][1] = (w0 >> 31) | (w1 << 33);
    rows[row][t][2] = (w0 >> 63) | (w1 << 1);
    rows[row][t][3] = w1 >> 31;
  }
  __syncthreads();
  const int X = threadIdx.x;
  const int dyy = threadIdx.y;
  const int Y = Y0 + dyy;
  const int sh = X & 31, wsel = X >> 5;
  // bilinear 2x skip taps (half-pixel, clamped) — baseline-exact f64
  const int y0 = (Y - 1) >> 1, x0 = (X - 1) >> 1;
  const double wy1 = (Y & 1) ? 0.25 : 0.75, wy0 = 1.0 - wy1;
  const double wx1 = (X & 1) ? 0.25 : 0.75, wx0 = 1.0 - wx1;
  const int iy0 = max(y0, 0), iy1 = min(y0 + 1, 63);
  const int ix0 = max(x0, 0), ix1 = min(x0 + 1, 63);
  const double ws[4] = { wy0 * wx0 * C_TAU1, wy0 * wx1 * C_TAU1,
                         wy1 * wx0 * C_TAU1, wy1 * wx1 * C_TAU1 };
  const unsigned long long* imb = im + (size_t)(b * 2 + o) * 4096;
  const unsigned long long ms[4] = {
    imb[(size_t)iy0 * 64 + ix0], imb[(size_t)iy0 * 64 + ix1],
    imb[(size_t)iy1 * 64 + ix0], imb[(size_t)iy1 * 64 + ix1] };
  unsigned mlo[4], mhi[4];
#pragma unroll
  for (int i = 0; i < 4; ++i) {
    mlo[i] = (unsigned)(ms[i] & 0xFFFFFFFFull);
    mhi[i] = (unsigned)(ms[i] >> 32);
  }
  double Ac = 0.0, Bc = 0.0, As = 0.0, Bs = 0.0;
  SpikeE st = {0.0, 0.0, 0u, 0u};
  for (int tt = 0; tt < 32; ++tt) {
    double dc = 0.0;
#pragma unroll
    for (int ky = 0; ky < 3; ++ky) {
      const unsigned long long wa = rows[0 * 4 + dyy + ky][tt][wsel];
      const unsigned long long wb = rows[1 * 4 + dyy + ky][tt][wsel];
      const unsigned f = (((unsigned)(wa >> sh)) & 7u)
                       | ((((unsigned)(wb >> sh)) & 7u) << 3);
      dc += tbl[ky][f];
    }
    double e = 0.0;
#pragma unroll
    for (int i = 0; i < 4; ++i)
      e += ws[i] * (double)((mlo[i] >> tt) & 1u);
    Bc = D_TAU4 * (Bc + Ac); Ac = D_TAU4 * Ac + dc;
    Bs = D_TAU1 * (Bs + As); As = D_TAU1 * As + e;
    spike_half0(st, Bc + Bs, tt, 100.0, DR3, CR3);
  }
  for (int tt = 0; tt < 32; ++tt) {
    double dc = 0.0;
#pragma unroll
    for (int ky = 0; ky < 3; ++ky) {
      const unsigned long long wa = rows[0 * 4 + dyy + ky][tt + 32][wsel];
      const unsigned long long wb = rows[1 * 4 + dyy + ky][tt + 32][wsel];
      const unsigned f = (((unsigned)(wa >> sh)) & 7u)
                       | ((((unsigned)(wb >> sh)) & 7u) << 3);
      dc += tbl[ky][f];
    }
    double e = 0.0;
#pragma unroll
    for (int i = 0; i < 4; ++i)
      e += ws[i] * (double)((mhi[i] >> tt) & 1u);
    Bc = D_TAU4 * (Bc + Ac); Ac = D_TAU4 * Ac + dc;
    Bs = D_TAU1 * (Bs + As); As = D_TAU1 * As + e;
    spike_half1(st, Bc + Bs, tt, 100.0, DR3, CR3, MD3, M32_3);
  }
  const unsigned long long h =
      ((unsigned long long)st.h1 << 32) | (unsigned long long)st.h0;
  // ---- coalesced output via wave shuffle ----
  // Wave covers X in [X0,X0+64) of row Y = contiguous 16 KB of out.
  // Chunk c: lane i writes float4 at float-offset c*256 + i*4, which is
  // site x_local = c*4 + (i>>4), bits t = (i&15)*4 .. +3 of that site's h.
  const int lane = X & 63;
  const int X0 = X & ~63;
  const int t0 = (lane & 15) * 4;
  float* wout = out + (((size_t)(b * 2 + o) * 128 + Y) * 128 + X0) * 64;
#pragma unroll
  for (int c = 0; c < 16; ++c) {
    const int src = c * 4 + (lane >> 4);
    const unsigned long long hh = __shfl(h, src, 64);
    const unsigned q = ((unsigned)(hh >> t0)) & 15u;
    float4 v;
    v.x = (q & 1u) ? 1.0f : 0.0f;
    v.y = (q & 2u) ? 1.0f : 0.0f;
    v.z = (q & 4u) ? 1.0f : 0.0f;
    v.w = (q & 8u) ? 1.0f : 0.0f;
    reinterpret_cast<float4*>(wout)[c * 64 + lane] = v;
  }
}

extern "C" void kernel_launch(void* const* d_in, const int* in_sizes, int n_in,
                              void* d_out, int out_size, void* d_ws, size_t ws_size,
                              hipStream_t stream) {
  const float* spikeIn = (const float*)d_in[0];   // (8,2,64,64,64) fp32
  const float* w1 = (const float*)d_in[1];        // (8,2,5,5)
  const float* w2 = (const float*)d_in[2];        // (8,2,2,2) = (in,out,i,j)
  const float* w3 = (const float*)d_in[3];        // (2,2,3,3)
  float* out = (float*)d_out;                     // (8,2,128,128,64) fp32

  // 4.5 MB total with lifetime-based aliasing (peak live set = 4.5 MB):
  unsigned long long* IM  = (unsigned long long*)d_ws;       // [0.0,0.5) MB
  unsigned long long* S1  = IM + (size_t)16 * 4096;          // [0.5,2.5) MB
  unsigned long long* S1C = S1 + (size_t)64 * 4096;          // [2.5,4.5) MB
  unsigned long long* IMT = S1C;   // alias: dead before K2b writes S1C
  unsigned long long* S2T = S1;    // alias: S1 dead after K2b

  k_masks<<<dim3(256), dim3(256), 0, stream>>>(spikeIn, IM, IMT);
  k_conv1_spike<<<dim3(16, 8, 8), dim3(256), 0, stream>>>(IMT, w1, S1);
  k_s1_bytes<<<dim3(128), dim3(256), 0, stream>>>(S1, S1C);
  k_deconv_spike<<<dim3(64, 1, 16), dim3(128, 2), 0, stream>>>(S1C, w2, S2T);
  k_conv3_spike_out<<<dim3(64, 1, 16), dim3(128, 2), 0, stream>>>(S2T, w3, IM, out);
}

// Round 6
// 162.469 us; speedup vs baseline: 1.4826x; 1.0709x over previous
//
#include <hip/hip_runtime.h>
#include <cstdint>
#include <cstddef>

// ---------------- numeric constants (fp64, 17 sig digits) ----------------
#define D_TAU1 0.36787944117144233   // exp(-1)
#define C_TAU1 2.7182818284590452    // e
#define D_TAU2 0.60653065971263342   // exp(-1/2)
#define C_TAU2 1.3591409142295226    // e/2
#define D_TAU4 0.77880078307140487   // exp(-1/4)
#define C_TAU4 0.67957045711476131   // e/4
#define DR1   0.36787944117144233
#define D32_1 1.2664165549094176e-14
#define CR1   -163.09690970754271
#define DR2   0.60653065971263342
#define D32_2 1.1253517471925911e-7
#define CR2   -135.91409142295226
#define DR3   0.77880078307140487
#define D32_3 3.3546262790251184e-4
#define CR3   -135.91409142295226
#define MD1   (-(D32_1 * CR1))
#define M32_1 (-(32.0 * D32_1 * CR1))
#define MD2   (-(D32_2 * CR2))
#define M32_2 (-(32.0 * D32_2 * CR2))
#define MD3   (-(D32_3 * CR3))
#define M32_3 (-(32.0 * D32_3 * CR3))

// ---------------- spike scan, 2-state refractory form (all f64) ----------
struct SpikeE { double P, Q; unsigned h0, h1; };

__device__ __forceinline__ void spike_half0(SpikeE& st, double u, int tt,
    double th, double dr, double CR) {
  const double v = u + st.P;
  const bool fire = (v >= th);
  const double u2 = st.P + st.Q;
  st.P = dr * u2;
  st.Q = dr * st.Q + (fire ? CR : 0.0);
  if (fire) st.h0 |= (1u << tt);
}
__device__ __forceinline__ void spike_half1(SpikeE& st, double u, int tt,
    double th, double dr, double CR, double MD, double M32) {
  const double v = u + st.P;
  const bool fire = (v >= th);
  const bool sd = (st.h0 >> tt) & 1u;
  const double u2 = st.P + st.Q;
  st.P = dr * u2 + (sd ? M32 : 0.0);
  st.Q = dr * st.Q + (fire ? (sd ? (CR + MD) : CR) : (sd ? MD : 0.0));
  if (fire) st.h1 |= (1u << tt);
}

// spread 32-bit -> 64-bit with stride 2 (bit k -> bit 2k)
__device__ __forceinline__ unsigned long long spread2(unsigned v) {
  unsigned long long x = v;
  x = (x | (x << 16)) & 0x0000FFFF0000FFFFull;
  x = (x | (x << 8))  & 0x00FF00FF00FF00FFull;
  x = (x | (x << 4))  & 0x0F0F0F0F0F0F0F0Full;
  x = (x | (x << 2))  & 0x3333333333333333ull;
  x = (x | (x << 1))  & 0x5555555555555555ull;
  return x;
}

// ---------------- workspace (4.5 MB, lifetime-aliased) -------------------
// IM  [0.0,0.5) MB : (16 img, 4096 sites) u64 input masks   — live all
// S1  [0.5,2.5) MB : (64 img, 4096 sites) u64 layer-1 masks — K2 -> K3
// S2T [2.5,4.5) MB : (16 img, 128 y, 2 xh, 64 t)            — K3 -> K4
// IMT = alias of S2T[0,0.5MB): x-transposed input — K1 -> K2 (dead before K3)

// K1: input spikes -> site masks + x-transposed bitplanes.
// Block = one (bc,y) image row (64 sites). Fully-coalesced float4 reads;
// per-site masks assembled via shfl-OR butterfly within 16-lane groups.
__global__ __launch_bounds__(256, 4) void k_masks(const float* __restrict__ x,
    unsigned long long* __restrict__ im, unsigned long long* __restrict__ imt) {
  __shared__ unsigned long long lm[64];
  const int tid = threadIdx.x;
  const int y = blockIdx.x, bc = blockIdx.y;
  const int w = tid >> 6, lane = tid & 63;
  const size_t rowf = ((size_t)bc * 64 + y) * 4096;   // row base in floats
  const float4* xin = reinterpret_cast<const float4*>(x + rowf);
  const int q = lane & 15, grp = lane >> 4;
#pragma unroll
  for (int j = 0; j < 4; ++j) {
    const float4 v = xin[w * 256 + j * 64 + lane];    // contiguous 1KB / wave
    unsigned nib = 0;
    if (v.x != 0.0f) nib |= 1u;
    if (v.y != 0.0f) nib |= 2u;
    if (v.z != 0.0f) nib |= 4u;
    if (v.w != 0.0f) nib |= 8u;
    unsigned long long m = (unsigned long long)nib << (q * 4);
    m |= __shfl_xor(m, 1, 64);
    m |= __shfl_xor(m, 2, 64);
    m |= __shfl_xor(m, 4, 64);
    m |= __shfl_xor(m, 8, 64);                        // all 16 lanes hold mask
    if (q == 0) lm[w * 16 + j * 4 + grp] = m;
  }
  __syncthreads();
  if (tid < 64) {
    const unsigned long long mask = lm[tid];
    im[((size_t)bc * 64 + y) * 64 + tid] = mask;      // dense 512B
    unsigned long long myw = 0ull;
    for (int t = 0; t < 64; ++t) {
      const unsigned long long bal = __ballot((int)((mask >> t) & 1ull));
      if (tid == t) myw = bal;
    }
    imt[((size_t)bc * 64 + y) * 64 + tid] = myw;
  }
}

// ---- K2: spike1 = spike(psp1(conv5x5(input))) — row-sum tables in LDS ----
__global__ __launch_bounds__(256, 4) void k_conv1_spike(
    const unsigned long long* __restrict__ imt, const float* __restrict__ w1f,
    unsigned long long* __restrict__ s1) {
  __shared__ double tbl[10][32];                   // [ch*5+r][5-bit field]
  __shared__ unsigned long long rows[16][64][2];   // [ch*8+rr][t][shift-variant]
  const int tid = threadIdx.x;
  const int o = blockIdx.y, b = blockIdx.z;
  const int y0 = blockIdx.x * 4;
  for (int i = tid; i < 320; i += 256) {
    const int f = i & 31, rr = i >> 5;
    double s = 0.0;
#pragma unroll
    for (int k = 0; k < 5; ++k)
      if ((f >> k) & 1) s += (double)w1f[o * 50 + rr * 5 + k] * C_TAU1;
    tbl[rr][f] = s;
  }
  for (int i = tid; i < 1024; i += 256) {
    const int t = i & 63, row = i >> 6;
    const int ch = row >> 3, rr = row & 7;
    const int yr = y0 - 2 + rr;
    unsigned long long w = 0ull;
    if ((unsigned)yr < 64u)
      w = imt[((size_t)(b * 2 + ch) * 64 + yr) * 64 + t];
    rows[row][t][0] = w << 2;
    rows[row][t][1] = w >> 30;
  }
  __syncthreads();
  const int x = tid & 63, dy = tid >> 6;
  const int y = y0 + dy;
  const int sh = x & 31, wsel = x >> 5;
  double A = 0.0, B = 0.0;
  SpikeE st = {0.0, 0.0, 0u, 0u};
  for (int tt = 0; tt < 32; ++tt) {
    double d = 0.0;
#pragma unroll
    for (int ch = 0; ch < 2; ++ch)
#pragma unroll
      for (int r = 0; r < 5; ++r) {
        const unsigned long long w = rows[ch * 8 + dy + r][tt][wsel];
        const unsigned f = ((unsigned)(w >> sh)) & 31u;
        d += tbl[ch * 5 + r][f];
      }
    B = D_TAU1 * (B + A); A = D_TAU1 * A + d;
    spike_half0(st, B, tt, 30.0, DR1, CR1);
  }
  for (int tt = 0; tt < 32; ++tt) {
    double d = 0.0;
#pragma unroll
    for (int ch = 0; ch < 2; ++ch)
#pragma unroll
      for (int r = 0; r < 5; ++r) {
        const unsigned long long w = rows[ch * 8 + dy + r][tt + 32][wsel];
        const unsigned f = ((unsigned)(w >> sh)) & 31u;
        d += tbl[ch * 5 + r][f];
      }
    B = D_TAU1 * (B + A); A = D_TAU1 * A + d;
    spike_half1(st, B, tt, 30.0, DR1, CR1, MD1, M32_1);
  }
  s1[((size_t)(b * 8 + o)) * 4096 + y * 64 + x] =
      ((unsigned long long)st.h1 << 32) | (unsigned long long)st.h0;
}

// ---- K3: spike2 = spike(deconv2x2(psp2(s1))); channel-byte pack fused ----
__global__ __launch_bounds__(256, 4) void k_deconv_spike(
    const unsigned long long* __restrict__ s1, const float* __restrict__ w2f,
    unsigned long long* __restrict__ s2t) {
  __shared__ double tbl[4][256];                   // [(ii*2+jj)][channel byte]
  __shared__ unsigned long long raw[8][64];        // [o][xi] site masks
  __shared__ unsigned long long packed[64][9];     // [xi][j] (+1 pad)
  const int tid = threadIdx.y * 128 + threadIdx.x;
  const int b = blockIdx.z >> 1, o = blockIdx.z & 1;
  const int yi = blockIdx.x;                       // site row
  for (int i = tid; i < 1024; i += 256) {
    const int f = i & 255, q = i >> 8, ii = q >> 1, jj = q & 1;
    double s = 0.0;
#pragma unroll
    for (int c = 0; c < 8; ++c)
      if ((f >> c) & 1) s += (double)w2f[((c * 2 + o) * 2 + ii) * 2 + jj] * C_TAU2;
    tbl[q][f] = s;
  }
  // stage the 8-channel site row (coalesced 512B per wave)
#pragma unroll
  for (int k = 0; k < 2; ++k) {
    const int idx = k * 256 + tid;
    const int oc = idx >> 6, xi = idx & 63;
    raw[oc][xi] = s1[((size_t)(b * 8 + oc)) * 4096 + yi * 64 + xi];
  }
  __syncthreads();
  // pack: per site, byte j over channels -> 8x8 bit transpose
  {
    const int site = tid >> 2, jp = tid & 3;
    unsigned long long m[8];
#pragma unroll
    for (int oc = 0; oc < 8; ++oc) m[oc] = raw[oc][site];
#pragma unroll
    for (int jj = 0; jj < 2; ++jj) {
      const int j = jp * 2 + jj;
      unsigned long long xx = 0ull;
#pragma unroll
      for (int oc = 0; oc < 8; ++oc)
        xx |= ((m[oc] >> (8 * j)) & 0xFFull) << (8 * oc);
      unsigned long long t;
      t = (xx ^ (xx >> 7)) & 0x00AA00AA00AA00AAull; xx = xx ^ t ^ (t << 7);
      t = (xx ^ (xx >> 14)) & 0x0000CCCC0000CCCCull; xx = xx ^ t ^ (t << 14);
      t = (xx ^ (xx >> 28)) & 0x00000000F0F0F0F0ull; xx = xx ^ t ^ (t << 28);
      packed[site][j] = xx;
    }
  }
  __syncthreads();
  const int X = threadIdx.x, Y = blockIdx.x * 2 + threadIdx.y;
  const int xi = X >> 1;
  const double* tq = tbl[(Y & 1) * 2 + (X & 1)];
  const unsigned long long c0 = packed[xi][0], c1 = packed[xi][1],
                           c2 = packed[xi][2], c3 = packed[xi][3],
                           c4 = packed[xi][4], c5 = packed[xi][5],
                           c6 = packed[xi][6], c7 = packed[xi][7];
  double A = 0.0, B = 0.0;
  SpikeE st = {0.0, 0.0, 0u, 0u};
#pragma unroll
  for (int tt = 0; tt < 32; ++tt) {
    const unsigned long long cword =
        (tt < 8) ? c0 : (tt < 16) ? c1 : (tt < 24) ? c2 : c3;
    const unsigned f = ((unsigned)(cword >> ((tt & 7) * 8))) & 255u;
    const double d = tq[f];
    B = D_TAU2 * (B + A); A = D_TAU2 * A + d;
    spike_half0(st, B, tt, 50.0, DR2, CR2);
  }
#pragma unroll
  for (int tt = 0; tt < 32; ++tt) {
    const unsigned long long cword =
        (tt < 8) ? c4 : (tt < 16) ? c5 : (tt < 24) ? c6 : c7;
    const unsigned f = ((unsigned)(cword >> ((tt & 7) * 8))) & 255u;
    const double d = tq[f];
    B = D_TAU2 * (B + A); A = D_TAU2 * A + d;
    spike_half1(st, B, tt, 50.0, DR2, CR2, MD2, M32_2);
  }
  // ballot-transpose out; layout [y][xh][t]: dense 512B per wave
  const int lane = threadIdx.x & 63, xh = threadIdx.x >> 6;
  unsigned long long myw = 0ull;
  for (int t = 0; t < 32; ++t) {
    const unsigned long long bal = __ballot((int)((st.h0 >> t) & 1u));
    if (lane == t) myw = bal;
  }
  for (int t = 0; t < 32; ++t) {
    const unsigned long long bal = __ballot((int)((st.h1 >> t) & 1u));
    if (lane == t + 32) myw = bal;
  }
  s2t[(((size_t)(b * 2 + o) * 128 + Y) * 2 + xh) * 64 + lane] = myw;
}

// ---- K4: out = spike(conv3x3(psp3(s2)) + psp1(bilinear(input))) ----
// ch-interleaved staged rows: one broadcast read + shift gives the 6-bit key.
__global__ __launch_bounds__(256, 4) void k_conv3_spike_out(
    const unsigned long long* __restrict__ s2t, const float* __restrict__ w3f,
    const unsigned long long* __restrict__ im, float* __restrict__ out) {
  __shared__ double tbl[3][64];                    // [ky][interleaved 6-bit key]
  __shared__ double skp[4][16];                    // [(Y&1)*2+(X&1)][4-bit key]
  __shared__ unsigned long long rowm[4][8][66];    // [rr][g][t] (+2 pad)
  const int tid = threadIdx.y * 128 + threadIdx.x;
  const int b = blockIdx.z >> 1, o = blockIdx.z & 1;
  const int Y0 = blockIdx.x * 2;
  // conv tables, interleaved key bit (kx*2+cc); add order (cc,kx) ascending
  for (int i = tid; i < 192; i += 256) {
    const int f = i & 63, ky = i >> 6;
    double s = 0.0;
#pragma unroll
    for (int cc = 0; cc < 2; ++cc)
#pragma unroll
      for (int kx = 0; kx < 3; ++kx)
        if ((f >> (kx * 2 + cc)) & 1)
          s += (double)w3f[o * 18 + cc * 9 + ky * 3 + kx] * C_TAU4;
    tbl[ky][f] = s;
  }
  // skip tables: 4 parity classes x 16 keys; add order i ascending
  for (int i = tid; i < 64; i += 256) {
    const int cls = i >> 4, key = i & 15;
    const double wy1 = (cls & 2) ? 0.25 : 0.75, wy0 = 1.0 - wy1;
    const double wx1 = (cls & 1) ? 0.25 : 0.75, wx0 = 1.0 - wx1;
    const double wsv[4] = { wy0 * wx0 * C_TAU1, wy0 * wx1 * C_TAU1,
                            wy1 * wx0 * C_TAU1, wy1 * wx1 * C_TAU1 };
    double s = 0.0;
#pragma unroll
    for (int k = 0; k < 4; ++k)
      if ((key >> k) & 1) s += wsv[k];
    skp[cls][key] = s;
  }
  // stage: one thread per (rr,t): interleave ch0/ch1 row bits (stride 2),
  // emit 8 pre-shifted 64-bit windows (window g serves x in [16g,16g+16)).
  {
    const int rr = tid >> 6, t = tid & 63;
    const int yn = Y0 - 1 + rr;
    unsigned long long a0 = 0, a1 = 0, b0 = 0, b1 = 0;
    if ((unsigned)yn < 128u) {
      const size_t base0 = (((size_t)(b * 2 + 0) * 128 + yn) * 2) * 64 + t;
      const size_t base1 = (((size_t)(b * 2 + 1) * 128 + yn) * 2) * 64 + t;
      a0 = s2t[base0]; a1 = s2t[base0 + 64];
      b0 = s2t[base1]; b1 = s2t[base1 + 64];
    }
    unsigned long long m0 = spread2((unsigned)a0)         | (spread2((unsigned)b0) << 1);
    unsigned long long m1 = spread2((unsigned)(a0 >> 32)) | (spread2((unsigned)(b0 >> 32)) << 1);
    unsigned long long m2 = spread2((unsigned)a1)         | (spread2((unsigned)b1) << 1);
    unsigned long long m3 = spread2((unsigned)(a1 >> 32)) | (spread2((unsigned)(b1 >> 32)) << 1);
    rowm[rr][0][t] = m0 << 2;
    rowm[rr][1][t] = (m0 >> 30) | (m1 << 34);
    rowm[rr][2][t] = (m0 >> 62) | (m1 << 2);
    rowm[rr][3][t] = (m1 >> 30) | (m2 << 34);
    rowm[rr][4][t] = (m1 >> 62) | (m2 << 2);
    rowm[rr][5][t] = (m2 >> 30) | (m3 << 34);
    rowm[rr][6][t] = (m2 >> 62) | (m3 << 2);
    rowm[rr][7][t] = m3 >> 30;
  }
  __syncthreads();
  const int X = threadIdx.x;
  const int dyy = threadIdx.y;
  const int Y = Y0 + dyy;
  const int g = X >> 4, sh2 = (X & 15) * 2;
  const double* sk = skp[dyy * 2 + (X & 1)];
  // bilinear 2x skip taps (half-pixel, clamped)
  const int y0 = (Y - 1) >> 1, x0 = (X - 1) >> 1;
  const int iy0 = max(y0, 0), iy1 = min(y0 + 1, 63);
  const int ix0 = max(x0, 0), ix1 = min(x0 + 1, 63);
  const unsigned long long* imb = im + (size_t)(b * 2 + o) * 4096;
  const unsigned long long ms[4] = {
    imb[(size_t)iy0 * 64 + ix0], imb[(size_t)iy0 * 64 + ix1],
    imb[(size_t)iy1 * 64 + ix0], imb[(size_t)iy1 * 64 + ix1] };
  unsigned mlo[4], mhi[4];
#pragma unroll
  for (int i = 0; i < 4; ++i) {
    mlo[i] = (unsigned)(ms[i] & 0xFFFFFFFFull);
    mhi[i] = (unsigned)(ms[i] >> 32);
  }
  double Ac = 0.0, Bc = 0.0, As = 0.0, Bs = 0.0;
  SpikeE st = {0.0, 0.0, 0u, 0u};
  for (int tt = 0; tt < 32; ++tt) {
    double dc = 0.0;
#pragma unroll
    for (int ky = 0; ky < 3; ++ky) {
      const unsigned long long w = rowm[dyy + ky][g][tt];
      const unsigned f = ((unsigned)(w >> sh2)) & 63u;
      dc += tbl[ky][f];
    }
    const unsigned kk = ((mlo[0] >> tt) & 1u) | (((mlo[1] >> tt) & 1u) << 1)
                      | (((mlo[2] >> tt) & 1u) << 2) | (((mlo[3] >> tt) & 1u) << 3);
    const double e = sk[kk];
    Bc = D_TAU4 * (Bc + Ac); Ac = D_TAU4 * Ac + dc;
    Bs = D_TAU1 * (Bs + As); As = D_TAU1 * As + e;
    spike_half0(st, Bc + Bs, tt, 100.0, DR3, CR3);
  }
  for (int tt = 0; tt < 32; ++tt) {
    double dc = 0.0;
#pragma unroll
    for (int ky = 0; ky < 3; ++ky) {
      const unsigned long long w = rowm[dyy + ky][g][tt + 32];
      const unsigned f = ((unsigned)(w >> sh2)) & 63u;
      dc += tbl[ky][f];
    }
    const unsigned kk = ((mhi[0] >> tt) & 1u) | (((mhi[1] >> tt) & 1u) << 1)
                      | (((mhi[2] >> tt) & 1u) << 2) | (((mhi[3] >> tt) & 1u) << 3);
    const double e = sk[kk];
    Bc = D_TAU4 * (Bc + Ac); Ac = D_TAU4 * Ac + dc;
    Bs = D_TAU1 * (Bs + As); As = D_TAU1 * As + e;
    spike_half1(st, Bc + Bs, tt, 100.0, DR3, CR3, MD3, M32_3);
  }
  const unsigned long long h =
      ((unsigned long long)st.h1 << 32) | (unsigned long long)st.h0;
  // coalesced output via wave shuffle: contiguous 1KB stores per instr
  const int lane = X & 63;
  const int X0 = X & ~63;
  const int t0 = (lane & 15) * 4;
  float* wout = out + (((size_t)(b * 2 + o) * 128 + Y) * 128 + X0) * 64;
#pragma unroll
  for (int c = 0; c < 16; ++c) {
    const int src = c * 4 + (lane >> 4);
    const unsigned long long hh = __shfl(h, src, 64);
    const unsigned q = ((unsigned)(hh >> t0)) & 15u;
    float4 v;
    v.x = (q & 1u) ? 1.0f : 0.0f;
    v.y = (q & 2u) ? 1.0f : 0.0f;
    v.z = (q & 4u) ? 1.0f : 0.0f;
    v.w = (q & 8u) ? 1.0f : 0.0f;
    reinterpret_cast<float4*>(wout)[c * 64 + lane] = v;
  }
}

extern "C" void kernel_launch(void* const* d_in, const int* in_sizes, int n_in,
                              void* d_out, int out_size, void* d_ws, size_t ws_size,
                              hipStream_t stream) {
  const float* spikeIn = (const float*)d_in[0];   // (8,2,64,64,64) fp32
  const float* w1 = (const float*)d_in[1];        // (8,2,5,5)
  const float* w2 = (const float*)d_in[2];        // (8,2,2,2) = (in,out,i,j)
  const float* w3 = (const float*)d_in[3];        // (2,2,3,3)
  float* out = (float*)d_out;                     // (8,2,128,128,64) fp32

  // 4.5 MB, lifetime-aliased (IMT dead before K3 writes S2T):
  unsigned long long* IM  = (unsigned long long*)d_ws;       // [0.0,0.5) MB
  unsigned long long* S1  = IM + (size_t)16 * 4096;          // [0.5,2.5) MB
  unsigned long long* S2T = S1 + (size_t)64 * 4096;          // [2.5,4.5) MB
  unsigned long long* IMT = S2T;   // alias

  k_masks<<<dim3(64, 16), dim3(256), 0, stream>>>(spikeIn, IM, IMT);
  k_conv1_spike<<<dim3(16, 8, 8), dim3(256), 0, stream>>>(IMT, w1, S1);
  k_deconv_spike<<<dim3(64, 1, 16), dim3(128, 2), 0, stream>>>(S1, w2, S2T);
  k_conv3_spike_out<<<dim3(64, 1, 16), dim3(128, 2), 0, stream>>>(S2T, w3, IM, out);
}